// Round 11
// baseline (43630.682 us; speedup 1.0000x reference)
//
#include <hip/hip_runtime.h>
#include <hip/hip_bf16.h>
#include <cstdint>

#define D_DIM 128
#define N0_C 50000
#define N1_C 5000
#define E0_C 800000
#define E1_C 80000
#define BIN_SHIFT 9          // 512 dst nodes per bin (graph0 fill)

typedef __attribute__((ext_vector_type(8))) short bf16x8;
typedef __attribute__((ext_vector_type(4))) float f32x4;
typedef __attribute__((ext_vector_type(2))) float f32x2;

__device__ __forceinline__ ushort f2bf_rne(float x) {
    unsigned int u = __float_as_uint(x);
    return (ushort)((u + 0x7FFFu + ((u >> 16) & 1u)) >> 16);
}
__device__ __forceinline__ float bf2f(ushort h) {
    return __uint_as_float(((unsigned int)h) << 16);
}
__device__ __forceinline__ int imin(int a, int b) { return a < b ? a : b; }
__device__ __forceinline__ void online2(float& m, float& s, float mo, float so) {
    if (mo > m) { s = s * __expf(m - mo) + so; m = mo; }
    else s += so * __expf(mo - m);
}

// ---------------------------------------------------------------------------
// prep: fused histogram over [dst0|dst1|ddst]  +  weight prep (independent)
// wt mats: 0:W0s 1:W0n 2:W1s 3:W1n 4:W2s_top 5:W2s_bot 6:W2n_top 7:W2n_bot
// ---------------------------------------------------------------------------
__global__ __launch_bounds__(256) void prep_kernel(
    const int* __restrict__ dst0, const int* __restrict__ dst1,
    const int* __restrict__ ddst, int* __restrict__ cnt,
    const float* __restrict__ W0s, const float* __restrict__ W0n,
    const float* __restrict__ W1s, const float* __restrict__ W1n,
    const float* __restrict__ W2s, const float* __restrict__ W2n,
    ushort* __restrict__ wt, int nbh) {
    int b = blockIdx.x, t = threadIdx.x;
    if (b < nbh) {
        int e = b * 256 + t;
        if (e < E0_C) atomicAdd(&cnt[dst0[e]], 1);
        else if (e < E0_C + E1_C) atomicAdd(&cnt[N0_C + dst1[e - E0_C]], 1);
        else if (e < E0_C + E1_C + N0_C) atomicAdd(&cnt[N0_C + N1_C + ddst[e - E0_C - E1_C]], 1);
    } else {
        int gi = (b - nbh) * 256 + t;
        int mi = gi >> 14, idx = gi & 16383;
        int k = idx >> 7, n = idx & 127;
        const float* src; int row = k;
        switch (mi) {
            case 0: src = W0s; break;
            case 1: src = W0n; break;
            case 2: src = W1s; break;
            case 3: src = W1n; break;
            case 4: src = W2s; break;
            case 5: src = W2s; row = k + 128; break;
            case 6: src = W2n; break;
            default: src = W2n; row = k + 128; break;
        }
        wt[(mi << 14) + n * 128 + k] = f2bf_rne(src[row * 128 + n]);
    }
}

// ---------------------------------------------------------------------------
// single-pass scan over cnt[n]: each block publishes its local total (packed
// +1 into a device-scope atomic flag), polls predecessors, writes rowptr
// (inclusive at [i+1]) + graph0 bin cursors. All blocks co-resident (n<=64k).
// ---------------------------------------------------------------------------
__global__ __launch_bounds__(256) void scan_onepass_kernel(
    const int* __restrict__ cnt, int* __restrict__ bflag,
    int* __restrict__ rowptr, int* __restrict__ cursors, int n) {
    __shared__ int wsum[4];
    __shared__ int boff_s;
    int b = blockIdx.x, t = threadIdx.x, lane = t & 63, w = t >> 6;
    int base = b * 1024 + t * 4;
    int v0 = 0, v1 = 0, v2 = 0, v3 = 0;
    if (base + 3 < n) { int4 q = *(const int4*)&cnt[base]; v0 = q.x; v1 = q.y; v2 = q.z; v3 = q.w; }
    else {
        if (base + 0 < n) v0 = cnt[base + 0];
        if (base + 1 < n) v1 = cnt[base + 1];
        if (base + 2 < n) v2 = cnt[base + 2];
        if (base + 3 < n) v3 = cnt[base + 3];
    }
    int s = v0 + v1 + v2 + v3;
    int x = s;
    #pragma unroll
    for (int off = 1; off < 64; off <<= 1) {
        int y = __shfl_up(x, off);
        if (lane >= off) x += y;
    }
    if (lane == 63) wsum[w] = x;
    __syncthreads();
    if (t == 0) {
        int run = 0;
        #pragma unroll
        for (int i = 0; i < 4; ++i) { int c = wsum[i]; wsum[i] = run; run += c; }
        atomicExch(&bflag[b], run + 1);          // publish local total (device scope)
    }
    // wave 0 polls predecessors, sums their totals
    if (w == 0) {
        int pv = 0;
        if (lane < b) {
            int v;
            while ((v = atomicAdd(&bflag[lane], 0)) == 0) {}
            pv = v - 1;
        }
        #pragma unroll
        for (int off = 32; off; off >>= 1) pv += __shfl_down(pv, off);
        if (lane == 0) boff_s = pv;
    }
    __syncthreads();
    int run = boff_s + wsum[w] + x - s;
    #pragma unroll
    for (int k = 0; k < 4; ++k) {
        int v = (k == 0) ? v0 : (k == 1) ? v1 : (k == 2) ? v2 : v3;
        int pos = base + k + 1;
        if (pos <= n) {
            run += v;
            rowptr[pos] = run;
            if ((pos & 511) == 0 && pos < N0_C) cursors[pos >> BIN_SHIFT] = run;
        }
    }
    if (b == 0 && t == 0) { rowptr[0] = 0; cursors[0] = 0; }
}

// ---------------------------------------------------------------------------
// scatfill: graph0 binned pair-scatter (blocks < nbscat) + small fills
// ---------------------------------------------------------------------------
__global__ __launch_bounds__(256) void scatfill_kernel(
    const int* __restrict__ src0, const int* __restrict__ dst0,
    const int* __restrict__ src1, const int* __restrict__ dst1,
    const int* __restrict__ dsrc, const int* __restrict__ ddst,
    const int* __restrict__ rowptrAll,
    int* __restrict__ cursors, int* __restrict__ pairs,
    int* __restrict__ cur1, int* __restrict__ curD,
    int* __restrict__ col1, int* __restrict__ colD,
    int nbscat, int nbins) {
    __shared__ int lcnt[128];
    __shared__ int sbase[128];
    int t = threadIdx.x;
    if (blockIdx.x < nbscat) {
        int e0 = blockIdx.x * 4096;
        if (t < 128) lcnt[t] = 0;
        __syncthreads();
        int lrank[16], dloc[16];
        #pragma unroll
        for (int i = 0; i < 16; ++i) {
            int e = e0 + t + i * 256;
            if (e < E0_C) {
                int d = dst0[e];
                dloc[i] = d;
                lrank[i] = atomicAdd(&lcnt[d >> BIN_SHIFT], 1);
            } else dloc[i] = -1;
        }
        __syncthreads();
        if (t < nbins && lcnt[t] > 0) sbase[t] = atomicAdd(&cursors[t], lcnt[t]);
        __syncthreads();
        #pragma unroll
        for (int i = 0; i < 16; ++i) {
            int e = e0 + t + i * 256;
            if (e < E0_C) {
                int d = dloc[i];
                int key = ((d & ((1 << BIN_SHIFT) - 1)) << 17) | src0[e];
                pairs[sbase[d >> BIN_SHIFT] + lrank[i]] = key;
            }
        }
    } else {
        int e = (blockIdx.x - nbscat) * 256 + t;
        if (e < E1_C) {
            int d = dst1[e];
            int p = atomicAdd(&cur1[d], 1);
            col1[rowptrAll[N0_C + d] - E0_C + p] = src1[e];
        } else if (e < E1_C + N0_C) {
            int i = e - E1_C;
            int d = ddst[i];
            int p = atomicAdd(&curD[d], 1);
            colD[rowptrAll[N0_C + N1_C + d] - E0_C - E1_C + p] = dsrc[i];
        }
    }
}

// ---------------------------------------------------------------------------
// fused: graph0 windowed colv fill (blocks < nbfill)  +  layer-0 dual GEMM
// (remaining blocks). Both depend only on {scatfill, prep}.
// dualmm: fp32 A hi/lo split, reg-resident B; O1 bf16 packed, O2 fp8 packed.
// ---------------------------------------------------------------------------
__global__ __launch_bounds__(256, 4) void binfill_dualmm_kernel(
    const int* __restrict__ pairs, const int* __restrict__ rowptr,
    int* __restrict__ colv, int Nfill, int nbfill,
    const float* __restrict__ A,
    const ushort* __restrict__ w1, const ushort* __restrict__ w2,
    const float* __restrict__ bias1,
    ushort* __restrict__ O1b, unsigned char* __restrict__ O2f8,
    int N, int ntiles) {
    __shared__ int rp[513];
    __shared__ int cur[512];
    const int tid = threadIdx.x;
    if (blockIdx.x < nbfill) {
        int b = blockIdx.x;
        int binbase = b << BIN_SHIFT;
        for (int i = tid; i < 513; i += 256) {
            int idx = binbase + i; if (idx > Nfill) idx = Nfill;
            rp[i] = rowptr[idx];
        }
        for (int i = tid; i < 512; i += 256) cur[i] = 0;
        __syncthreads();
        int beg = rp[0], end = rp[512];
        for (int i = beg + tid; i < end; i += 256) {
            int key = pairs[i];
            int local = key >> 17;
            int rank = atomicAdd(&cur[local], 1);
            colv[rp[local] + rank] = key & 0x1FFFF;
        }
        return;
    }
    // ---- dualmm part ----
    const int gstride = gridDim.x - nbfill;
    const int bid = blockIdx.x - nbfill;
    const int wave = tid >> 6, lane = tid & 63;
    const int m = lane & 15, quad = lane >> 4;
    const int colbase = wave * 32;
    bf16x8 bf[4][2][2];
    #pragma unroll
    for (int c = 0; c < 4; ++c)
        #pragma unroll
        for (int ct = 0; ct < 2; ++ct) {
            const size_t bo = (size_t)(colbase + ct * 16 + m) * 128 + c * 32 + quad * 8;
            bf[c][ct][0] = *(const bf16x8*)(w1 + bo);
            bf[c][ct][1] = *(const bf16x8*)(w2 + bo);
        }
    const f32x4 zero = {0.f, 0.f, 0.f, 0.f};
    for (int tile = bid; tile < ntiles; tile += gstride) {
        const int r0 = tile * 16;
        int ar = r0 + m; if (ar >= N) ar = N - 1;
        const float* arow = A + (size_t)ar * 128;
        f32x4 acc[2][2];
        acc[0][0] = zero; acc[0][1] = zero; acc[1][0] = zero; acc[1][1] = zero;
        #pragma unroll
        for (int c = 0; c < 4; ++c) {
            float4 a0 = *(const float4*)(arow + c * 32 + quad * 8);
            float4 a1 = *(const float4*)(arow + c * 32 + quad * 8 + 4);
            float av[8] = {a0.x, a0.y, a0.z, a0.w, a1.x, a1.y, a1.z, a1.w};
            bf16x8 afh, afl;
            #pragma unroll
            for (int i = 0; i < 8; ++i) {
                ushort h = f2bf_rne(av[i]);
                ushort l = f2bf_rne(av[i] - bf2f(h));
                afh[i] = (short)h; afl[i] = (short)l;
            }
            #pragma unroll
            for (int ct = 0; ct < 2; ++ct) {
                acc[ct][0] = __builtin_amdgcn_mfma_f32_16x16x32_bf16(afh, bf[c][ct][0], acc[ct][0], 0, 0, 0);
                acc[ct][0] = __builtin_amdgcn_mfma_f32_16x16x32_bf16(afl, bf[c][ct][0], acc[ct][0], 0, 0, 0);
                acc[ct][1] = __builtin_amdgcn_mfma_f32_16x16x32_bf16(afh, bf[c][ct][1], acc[ct][1], 0, 0, 0);
                acc[ct][1] = __builtin_amdgcn_mfma_f32_16x16x32_bf16(afl, bf[c][ct][1], acc[ct][1], 0, 0, 0);
            }
        }
        #pragma unroll
        for (int ct = 0; ct < 2; ++ct) {
            const int col = colbase + ct * 16 + m;
            float bv = bias1 ? bias1[col] : 0.f;
            #pragma unroll
            for (int reg = 0; reg < 4; ++reg) {
                int r = r0 + quad * 4 + reg;
                float o1 = acc[ct][0][reg] + bv;
                float o2 = acc[ct][1][reg];
                uint u1 = f2bf_rne(o1);
                uint p1 = (uint)__shfl_xor((int)u1, 1);
                float o2n = __shfl_xor(o2, 1);
                int pk = __builtin_amdgcn_cvt_pk_fp8_f32(o2, o2n, 0, false);
                int pk2 = __shfl_xor(pk, 2);
                if (r < N) {
                    if (!(m & 1)) *(uint*)&O1b[(size_t)r * D_DIM + col] = u1 | (p1 << 16);
                    if (!(m & 3)) *(uint*)&O2f8[(size_t)r * D_DIM + col] =
                        ((uint)pk & 0xFFFFu) | ((uint)pk2 << 16);
                }
            }
        }
    }
}

// ---------------------------------------------------------------------------
// standalone dual GEMM, fp32 A (hi/lo split), fp32 outs (layer-2 small C2/D2)
// ---------------------------------------------------------------------------
__global__ __launch_bounds__(256, 4) void dualmm_reg_kernel(
    const float* __restrict__ A,
    const ushort* __restrict__ w1, const ushort* __restrict__ w2,
    const float* __restrict__ bias1,
    float* __restrict__ O1f, float* __restrict__ O2f, int N, int ntiles) {
    const int tid = threadIdx.x;
    const int wave = tid >> 6, lane = tid & 63;
    const int m = lane & 15, quad = lane >> 4;
    const int colbase = wave * 32;
    bf16x8 bf[4][2][2];
    #pragma unroll
    for (int c = 0; c < 4; ++c)
        #pragma unroll
        for (int ct = 0; ct < 2; ++ct) {
            const size_t bo = (size_t)(colbase + ct * 16 + m) * 128 + c * 32 + quad * 8;
            bf[c][ct][0] = *(const bf16x8*)(w1 + bo);
            bf[c][ct][1] = *(const bf16x8*)(w2 + bo);
        }
    const f32x4 zero = {0.f, 0.f, 0.f, 0.f};
    for (int tile = blockIdx.x; tile < ntiles; tile += gridDim.x) {
        const int r0 = tile * 16;
        int ar = r0 + m; if (ar >= N) ar = N - 1;
        const float* arow = A + (size_t)ar * 128;
        f32x4 acc[2][2];
        acc[0][0] = zero; acc[0][1] = zero; acc[1][0] = zero; acc[1][1] = zero;
        #pragma unroll
        for (int c = 0; c < 4; ++c) {
            float4 a0 = *(const float4*)(arow + c * 32 + quad * 8);
            float4 a1 = *(const float4*)(arow + c * 32 + quad * 8 + 4);
            float av[8] = {a0.x, a0.y, a0.z, a0.w, a1.x, a1.y, a1.z, a1.w};
            bf16x8 afh, afl;
            #pragma unroll
            for (int i = 0; i < 8; ++i) {
                ushort h = f2bf_rne(av[i]);
                ushort l = f2bf_rne(av[i] - bf2f(h));
                afh[i] = (short)h; afl[i] = (short)l;
            }
            #pragma unroll
            for (int ct = 0; ct < 2; ++ct) {
                acc[ct][0] = __builtin_amdgcn_mfma_f32_16x16x32_bf16(afh, bf[c][ct][0], acc[ct][0], 0, 0, 0);
                acc[ct][0] = __builtin_amdgcn_mfma_f32_16x16x32_bf16(afl, bf[c][ct][0], acc[ct][0], 0, 0, 0);
                acc[ct][1] = __builtin_amdgcn_mfma_f32_16x16x32_bf16(afh, bf[c][ct][1], acc[ct][1], 0, 0, 0);
                acc[ct][1] = __builtin_amdgcn_mfma_f32_16x16x32_bf16(afl, bf[c][ct][1], acc[ct][1], 0, 0, 0);
            }
        }
        #pragma unroll
        for (int ct = 0; ct < 2; ++ct) {
            const int col = colbase + ct * 16 + m;
            float bv = bias1 ? bias1[col] : 0.f;
            #pragma unroll
            for (int reg = 0; reg < 4; ++reg) {
                int r = r0 + quad * 4 + reg;
                if (r < N) {
                    size_t o = (size_t)r * D_DIM + col;
                    O1f[o] = acc[ct][0][reg] + bv;
                    O2f[o] = acc[ct][1][reg];
                }
            }
        }
    }
}

// bf16-A variant: optional bias, optional C2/D2 gather-add, fp32 or bf16+fp8 outs
__global__ __launch_bounds__(256, 4) void dualmm_regb_kernel(
    const ushort* __restrict__ Ab,
    const ushort* __restrict__ w1, const ushort* __restrict__ w2,
    const float* __restrict__ bias1,
    const int* __restrict__ ddst,
    const float* __restrict__ C2g, const float* __restrict__ D2g,
    float* __restrict__ O1f, ushort* __restrict__ O1b,
    float* __restrict__ O2f, unsigned char* __restrict__ O2f8,
    int N, int ntiles) {
    const int tid = threadIdx.x;
    const int wave = tid >> 6, lane = tid & 63;
    const int m = lane & 15, quad = lane >> 4;
    const int colbase = wave * 32;
    bf16x8 bf[4][2][2];
    #pragma unroll
    for (int c = 0; c < 4; ++c)
        #pragma unroll
        for (int ct = 0; ct < 2; ++ct) {
            const size_t bo = (size_t)(colbase + ct * 16 + m) * 128 + c * 32 + quad * 8;
            bf[c][ct][0] = *(const bf16x8*)(w1 + bo);
            bf[c][ct][1] = *(const bf16x8*)(w2 + bo);
        }
    const f32x4 zero = {0.f, 0.f, 0.f, 0.f};
    for (int tile = blockIdx.x; tile < ntiles; tile += gridDim.x) {
        const int r0 = tile * 16;
        int ar = r0 + m; if (ar >= N) ar = N - 1;
        const ushort* arow = Ab + (size_t)ar * 128;
        f32x4 acc[2][2];
        acc[0][0] = zero; acc[0][1] = zero; acc[1][0] = zero; acc[1][1] = zero;
        #pragma unroll
        for (int c = 0; c < 4; ++c) {
            bf16x8 af = *(const bf16x8*)(arow + c * 32 + quad * 8);
            #pragma unroll
            for (int ct = 0; ct < 2; ++ct) {
                acc[ct][0] = __builtin_amdgcn_mfma_f32_16x16x32_bf16(af, bf[c][ct][0], acc[ct][0], 0, 0, 0);
                acc[ct][1] = __builtin_amdgcn_mfma_f32_16x16x32_bf16(af, bf[c][ct][1], acc[ct][1], 0, 0, 0);
            }
        }
        int rr[4], cc[4];
        #pragma unroll
        for (int reg = 0; reg < 4; ++reg) {
            rr[reg] = r0 + quad * 4 + reg;
            cc[reg] = (ddst && rr[reg] < N) ? ddst[rr[reg]] : 0;
        }
        #pragma unroll
        for (int ct = 0; ct < 2; ++ct) {
            const int col = colbase + ct * 16 + m;
            float bv = bias1 ? bias1[col] : 0.f;
            #pragma unroll
            for (int reg = 0; reg < 4; ++reg) {
                int r = rr[reg];
                float g1 = (ddst && r < N) ? C2g[(size_t)cc[reg] * D_DIM + col] : 0.f;
                float g2 = (ddst && r < N) ? D2g[(size_t)cc[reg] * D_DIM + col] : 0.f;
                float o1 = acc[ct][0][reg] + bv + g1;
                float o2 = acc[ct][1][reg] + g2;
                if (O1b) {
                    uint u1 = f2bf_rne(o1);
                    uint p1 = (uint)__shfl_xor((int)u1, 1);
                    float o2n = __shfl_xor(o2, 1);
                    int pk = __builtin_amdgcn_cvt_pk_fp8_f32(o2, o2n, 0, false);
                    int pk2 = __shfl_xor(pk, 2);
                    if (r < N) {
                        if (!(m & 1)) *(uint*)&O1b[(size_t)r * D_DIM + col] = u1 | (p1 << 16);
                        if (!(m & 3)) *(uint*)&O2f8[(size_t)r * D_DIM + col] =
                            ((uint)pk & 0xFFFFu) | ((uint)pk2 << 16);
                    }
                } else if (r < N) {
                    size_t o = (size_t)r * D_DIM + col;
                    O1f[o] = o1; O2f[o] = o2;
                }
            }
        }
    }
}

// ---------------------------------------------------------------------------
// fp32 CSR gather-aggregate (small graph1): wave/node, float4/lane
// ---------------------------------------------------------------------------
__global__ __launch_bounds__(256) void csr_agg2_kernel(
    const float* __restrict__ feat, const int* __restrict__ rowptr, int rbase,
    const int* __restrict__ colv, const float* __restrict__ addv,
    float* __restrict__ out, int Ndst, int do_relu) {
    int gt = blockIdx.x * blockDim.x + threadIdx.x;
    int wid = gt >> 6;
    if (wid >= Ndst) return;
    int lane = threadIdx.x & 63;
    int half = lane >> 5, li = lane & 31;
    const int f4 = li * 4;
    float4 acc = make_float4(0.f, 0.f, 0.f, 0.f);
    int beg = rowptr[wid] - rbase, end = rowptr[wid + 1] - rbase;
    int deg = end - beg;
    for (int j = beg + half; j < end; j += 8) {
        int i1 = imin(j + 2, end - 1), i2 = imin(j + 4, end - 1), i3 = imin(j + 6, end - 1);
        int r0 = colv[j], r1 = colv[i1], r2 = colv[i2], r3 = colv[i3];
        float4 v0 = *(const float4*)&feat[(size_t)r0 * D_DIM + f4];
        float4 v1 = *(const float4*)&feat[(size_t)r1 * D_DIM + f4];
        float4 v2 = *(const float4*)&feat[(size_t)r2 * D_DIM + f4];
        float4 v3 = *(const float4*)&feat[(size_t)r3 * D_DIM + f4];
        acc.x += v0.x; acc.y += v0.y; acc.z += v0.z; acc.w += v0.w;
        if (j + 2 < end) { acc.x += v1.x; acc.y += v1.y; acc.z += v1.z; acc.w += v1.w; }
        if (j + 4 < end) { acc.x += v2.x; acc.y += v2.y; acc.z += v2.z; acc.w += v2.w; }
        if (j + 6 < end) { acc.x += v3.x; acc.y += v3.y; acc.z += v3.z; acc.w += v3.w; }
    }
    acc.x += __shfl_xor(acc.x, 32);
    acc.y += __shfl_xor(acc.y, 32);
    acc.z += __shfl_xor(acc.z, 32);
    acc.w += __shfl_xor(acc.w, 32);
    float invd = 1.f / fmaxf((float)deg, 1.f);
    acc.x *= invd; acc.y *= invd; acc.z *= invd; acc.w *= invd;
    if (addv) {
        float4 v = *(const float4*)&addv[(size_t)wid * D_DIM + f4];
        acc.x += v.x; acc.y += v.y; acc.z += v.z; acc.w += v.w;
    }
    if (do_relu) {
        acc.x = fmaxf(acc.x, 0.f); acc.y = fmaxf(acc.y, 0.f);
        acc.z = fmaxf(acc.z, 0.f); acc.w = fmaxf(acc.w, 0.f);
    }
    if (half == 0)
        *(float4*)&out[(size_t)wid * D_DIM + f4] = acc;
}

// ---------------------------------------------------------------------------
// big CSR gather-aggregate, 2 nodes/wave; FP8 plane or bf16 plane. Optional
// fused readout z=...@Wm+bm AND online-softmax partial merge (packed CAS).
// NOTE: launched only with Ndst divisible by 8 -> no early-exit waves, so the
// block-level __syncthreads in the softmax path is safe.
// ---------------------------------------------------------------------------
__device__ __forceinline__ void acc8_add_bf(float* acc, uint4 r) {
    acc[0] += __uint_as_float(r.x << 16);
    acc[1] += __uint_as_float(r.x & 0xFFFF0000u);
    acc[2] += __uint_as_float(r.y << 16);
    acc[3] += __uint_as_float(r.y & 0xFFFF0000u);
    acc[4] += __uint_as_float(r.z << 16);
    acc[5] += __uint_as_float(r.z & 0xFFFF0000u);
    acc[6] += __uint_as_float(r.w << 16);
    acc[7] += __uint_as_float(r.w & 0xFFFF0000u);
}
__device__ __forceinline__ void acc8_add_f8(float* acc, uint2 r) {
    f32x2 a = __builtin_amdgcn_cvt_pk_f32_fp8((int)r.x, false);
    f32x2 b = __builtin_amdgcn_cvt_pk_f32_fp8((int)r.x, true);
    f32x2 c = __builtin_amdgcn_cvt_pk_f32_fp8((int)r.y, false);
    f32x2 d = __builtin_amdgcn_cvt_pk_f32_fp8((int)r.y, true);
    acc[0] += a[0]; acc[1] += a[1]; acc[2] += b[0]; acc[3] += b[1];
    acc[4] += c[0]; acc[5] += c[1]; acc[6] += d[0]; acc[7] += d[1];
}

template <int FP8>
__global__ __launch_bounds__(256) void csr_agg_big(
    const void* __restrict__ featv, const int* __restrict__ rowptr, int rbase,
    const int* __restrict__ colv,
    const ushort* __restrict__ addvb, const float* __restrict__ bias,
    ushort* __restrict__ outb,
    const float* __restrict__ Wm, const float* __restrict__ bm,
    float* __restrict__ z, unsigned long long* __restrict__ redpack,
    int Ndst, int do_relu) {
    __shared__ float smm[4], sss[4];
    const char* feat = (const char*)featv;
    int gt = blockIdx.x * blockDim.x + threadIdx.x;
    int wp = gt >> 6;
    int nA = wp * 2;
    if (nA >= Ndst) return;
    int nB = nA + 1;
    bool hasB = (nB < Ndst);
    int lane = threadIdx.x & 63;
    int q = lane >> 4, li = lane & 15;
    float accA[8], accB[8];
    #pragma unroll
    for (int i = 0; i < 8; ++i) { accA[i] = 0.f; accB[i] = 0.f; }
    int begA = rowptr[nA] - rbase, endA = rowptr[nA + 1] - rbase;
    int begB = 0, endB = 0;
    if (hasB) { begB = endA; endB = rowptr[nB + 1] - rbase; }
    int degA = endA - begA, degB = endB - begB;
    int lastA = (degA > 0) ? endA - 1 : 0;
    int lastB = (degB > 0) ? endB - 1 : 0;
    int jA = begA + q, jB = begB + q;
    while (jA < endA || jB < endB) {
        int ia[4], ib[4];
        #pragma unroll
        for (int k = 0; k < 4; ++k) {
            ia[k] = imin(jA + 4 * k, lastA);
            ib[k] = imin(jB + 4 * k, lastB);
        }
        if (FP8) {
            uint2 va[4], vb[4];
            #pragma unroll
            for (int k = 0; k < 4; ++k) {
                int ra = colv[ia[k]];
                va[k] = *(const uint2*)(feat + (size_t)ra * 128 + li * 8);
            }
            #pragma unroll
            for (int k = 0; k < 4; ++k) {
                int rb = colv[ib[k]];
                vb[k] = *(const uint2*)(feat + (size_t)rb * 128 + li * 8);
            }
            #pragma unroll
            for (int k = 0; k < 4; ++k) {
                if (jA + 4 * k < endA) acc8_add_f8(accA, va[k]);
                if (jB + 4 * k < endB) acc8_add_f8(accB, vb[k]);
            }
        } else {
            uint4 va[4], vb[4];
            #pragma unroll
            for (int k = 0; k < 4; ++k) {
                int ra = colv[ia[k]];
                va[k] = *(const uint4*)(feat + (size_t)ra * 256 + li * 16);
            }
            #pragma unroll
            for (int k = 0; k < 4; ++k) {
                int rb = colv[ib[k]];
                vb[k] = *(const uint4*)(feat + (size_t)rb * 256 + li * 16);
            }
            #pragma unroll
            for (int k = 0; k < 4; ++k) {
                if (jA + 4 * k < endA) acc8_add_bf(accA, va[k]);
                if (jB + 4 * k < endB) acc8_add_bf(accB, vb[k]);
            }
        }
        jA += 16; jB += 16;
    }
    const int f8 = li * 8;
    #pragma unroll
    for (int i = 0; i < 8; ++i) {
        accA[i] += __shfl_xor(accA[i], 16);
        accA[i] += __shfl_xor(accA[i], 32);
        accB[i] += __shfl_xor(accB[i], 16);
        accB[i] += __shfl_xor(accB[i], 32);
    }
    float invA = 1.f / fmaxf((float)degA, 1.f);
    float invB = 1.f / fmaxf((float)degB, 1.f);
    #pragma unroll
    for (int i = 0; i < 8; ++i) { accA[i] *= invA; accB[i] *= invB; }
    if (addvb) {
        uint4 a = *(const uint4*)&addvb[(size_t)nA * D_DIM + f8];
        acc8_add_bf(accA, a);
        if (hasB) {
            uint4 b = *(const uint4*)&addvb[(size_t)nB * D_DIM + f8];
            acc8_add_bf(accB, b);
        }
    }
    if (bias) {
        float4 b0 = *(const float4*)&bias[f8];
        float4 b1 = *(const float4*)&bias[f8 + 4];
        accA[0] += b0.x; accA[1] += b0.y; accA[2] += b0.z; accA[3] += b0.w;
        accA[4] += b1.x; accA[5] += b1.y; accA[6] += b1.z; accA[7] += b1.w;
        accB[0] += b0.x; accB[1] += b0.y; accB[2] += b0.z; accB[3] += b0.w;
        accB[4] += b1.x; accB[5] += b1.y; accB[6] += b1.z; accB[7] += b1.w;
    }
    if (do_relu) {
        #pragma unroll
        for (int i = 0; i < 8; ++i) {
            accA[i] = fmaxf(accA[i], 0.f);
            accB[i] = fmaxf(accB[i], 0.f);
        }
    }
    if (outb) {
        if (q == 0) {
            uint4 o;
            o.x = (uint)f2bf_rne(accA[0]) | ((uint)f2bf_rne(accA[1]) << 16);
            o.y = (uint)f2bf_rne(accA[2]) | ((uint)f2bf_rne(accA[3]) << 16);
            o.z = (uint)f2bf_rne(accA[4]) | ((uint)f2bf_rne(accA[5]) << 16);
            o.w = (uint)f2bf_rne(accA[6]) | ((uint)f2bf_rne(accA[7]) << 16);
            *(uint4*)&outb[(size_t)nA * D_DIM + f8] = o;
        } else if (q == 1 && hasB) {
            uint4 o;
            o.x = (uint)f2bf_rne(accB[0]) | ((uint)f2bf_rne(accB[1]) << 16);
            o.y = (uint)f2bf_rne(accB[2]) | ((uint)f2bf_rne(accB[3]) << 16);
            o.z = (uint)f2bf_rne(accB[4]) | ((uint)f2bf_rne(accB[5]) << 16);
            o.w = (uint)f2bf_rne(accB[6]) | ((uint)f2bf_rne(accB[7]) << 16);
            *(uint4*)&outb[(size_t)nB * D_DIM + f8] = o;
        }
    }
    if (z) {
        float4 w0 = *(const float4*)&Wm[f8];
        float4 w1 = *(const float4*)&Wm[f8 + 4];
        float p = 0.f;
        if (q == 0)
            p = accA[0] * w0.x + accA[1] * w0.y + accA[2] * w0.z + accA[3] * w0.w
              + accA[4] * w1.x + accA[5] * w1.y + accA[6] * w1.z + accA[7] * w1.w;
        else if (q == 1)
            p = accB[0] * w0.x + accB[1] * w0.y + accB[2] * w0.z + accB[3] * w0.w
              + accB[4] * w1.x + accB[5] * w1.y + accB[6] * w1.z + accB[7] * w1.w;
        #pragma unroll
        for (int off = 8; off > 0; off >>= 1) p += __shfl_down(p, off);
        float zval = p + bm[0];
        if (lane == 0) z[nA] = zval;
        if (lane == 16 && hasB) z[nB] = zval;
        // ---- fused online-softmax partial (block -> packed CAS merge) ----
        float m = -1e30f, s = 0.f;
        if (lane == 0) { m = zval; s = 1.f; }
        if (lane == 16 && hasB) { m = zval; s = 1.f; }
        #pragma unroll
        for (int off = 32; off; off >>= 1) {
            float mo = __shfl_xor(m, off), so = __shfl_xor(s, off);
            online2(m, s, mo, so);
        }
        int wv = threadIdx.x >> 6;
        if (lane == 0) { smm[wv] = m; sss[wv] = s; }
        __syncthreads();
        if (threadIdx.x == 0) {
            #pragma unroll
            for (int i = 1; i < 4; ++i) online2(m, s, smm[i], sss[i]);
            unsigned long long old = atomicAdd(redpack, 0ULL), assumed;
            do {
                assumed = old;
                float mo = __uint_as_float((unsigned)(assumed >> 32));
                float so = __uint_as_float((unsigned)(assumed & 0xFFFFFFFFu));
                float mn = m, sn = s;
                online2(mn, sn, mo, so);
                unsigned long long nv =
                    ((unsigned long long)__float_as_uint(mn) << 32) | __float_as_uint(sn);
                if (nv == assumed) break;
                old = atomicCAS(redpack, assumed, nv);
            } while (old != assumed);
        }
    }
}

__global__ __launch_bounds__(256) void softmax_final_kernel(
    const float* __restrict__ z, const unsigned long long* __restrict__ redpack,
    float* __restrict__ out, int N) {
    unsigned long long pack = *redpack;
    float m = __uint_as_float((unsigned)(pack >> 32));
    float s = __uint_as_float((unsigned)(pack & 0xFFFFFFFFu));
    for (int i = blockIdx.x * 256 + threadIdx.x; i < N; i += gridDim.x * 256)
        out[i] = expf(z[i] - m) / s;
}

// ---------------------------------------------------------------------------
// Host launcher
// ---------------------------------------------------------------------------
static inline char* align_up(char* p, size_t a) {
    return (char*)(((uintptr_t)p + a - 1) & ~(uintptr_t)(a - 1));
}

extern "C" void kernel_launch(void* const* d_in, const int* in_sizes, int n_in,
                              void* d_out, int out_size, void* d_ws, size_t ws_size,
                              hipStream_t stream) {
    const int N0 = N0_C, N1 = N1_C, E0 = E0_C, E1 = E1_C;
    const float* X   = (const float*)d_in[0];
    const float* W0s = (const float*)d_in[1];
    const float* W0n = (const float*)d_in[2];
    const float* b0  = (const float*)d_in[3];
    const float* W1s = (const float*)d_in[4];
    const float* W1n = (const float*)d_in[5];
    const float* b1  = (const float*)d_in[6];
    const float* W2s = (const float*)d_in[7];
    const float* W2n = (const float*)d_in[8];
    const float* b2  = (const float*)d_in[9];
    const float* Wm  = (const float*)d_in[10];
    const float* bm  = (const float*)d_in[11];
    const int* src0  = (const int*)d_in[12];
    const int* dst0  = (const int*)d_in[13];
    const int* src1  = (const int*)d_in[14];
    const int* dst1  = (const int*)d_in[15];
    const int* dsrc  = (const int*)d_in[16];
    const int* ddst  = (const int*)d_in[17];
    float* out = (float*)d_out;

    char* p = (char*)d_ws;
    const size_t FB = (size_t)N0 * D_DIM;
    const size_t SB = (size_t)N1 * D_DIM;
    auto grab_f = [&](size_t nf) { p = align_up(p, 256); float* r = (float*)p; p += nf * 4; return r; };
    auto grab_i = [&](size_t ni) { p = align_up(p, 256); int* r = (int*)p; p += ni * 4; return r; };
    auto grab_u = [&](size_t nu) { p = align_up(p, 256); ushort* r = (ushort*)p; p += nu * 2; return r; };
    auto grab_b = [&](size_t nb) { p = align_up(p, 256); unsigned char* r = (unsigned char*)p; p += nb; return r; };

    const int NC = N0 + 2 * N1;
    // zero-init region: [cntAll NC | cnt2 N1 | cntD2 N1 | bflag 64 | redpack 2]
    int* zeroRegion = grab_i((size_t)NC + 2 * N1 + 64 + 2);
    int* cntAll = zeroRegion;
    int* cnt2 = zeroRegion + NC;
    int* cntD2 = zeroRegion + NC + N1;
    int* bflag = zeroRegion + NC + 2 * N1;
    unsigned long long* redpack = (unsigned long long*)(zeroRegion + NC + 2 * N1 + 64);

    float* y1s  = grab_f(SB);   // -> x1f
    float* y1n  = grab_f(SB);
    float* C2   = grab_f(SB);
    float* D2   = grab_f(SB);
    float* zbuf = grab_f(N0);
    ushort* y0sb = grab_u(FB);
    ushort* x0b  = grab_u(FB);
    ushort* y2sb = grab_u(FB);
    ushort* x1bb = grab_u(SB);
    unsigned char* y0nf8 = grab_b(FB);
    unsigned char* y2nf8 = grab_b(FB);
    ushort* wt   = grab_u(8 * 16384);
    int* rowptrAll = grab_i(NC + 1);
    int* cursors = grab_i(128);
    int* col0 = grab_i(E0);
    int* col1 = grab_i(E1);
    int* colD = grab_i(N0);
    int* pairbuf = grab_i((size_t)E0);
    (void)ws_size; (void)n_in; (void)in_sizes; (void)out_size;

    const int BT = 256;
    auto cdiv = [](int a, int b) { return (a + b - 1) / b; };
    auto WT = [&](int mi) { return wt + ((size_t)mi << 14); };
    const int nbins0 = (N0 + (1 << BIN_SHIFT) - 1) >> BIN_SHIFT;   // 98
    const int nt0 = cdiv(N0, 16);
    const int nt1 = cdiv(N1, 16);
    const int G0 = 1024;

    // ---- one memset for all counters/flags/softmax accumulator ----
    hipMemsetAsync(zeroRegion, 0, ((size_t)NC + 2 * N1 + 64 + 2) * 4, stream);

    // ---- CSR build + weight prep ----
    const int nbh = cdiv(E0 + E1 + N0, BT);
    prep_kernel<<<nbh + 512, BT, 0, stream>>>(dst0, dst1, ddst, cntAll,
        W0s, W0n, W1s, W1n, W2s, W2n, wt, nbh);
    const int NB = cdiv(NC, 1024);                     // 59 blocks, co-resident
    scan_onepass_kernel<<<NB, BT, 0, stream>>>(cntAll, bflag, rowptrAll, cursors, NC);
    const int nbscat = cdiv(E0, 4096);
    scatfill_kernel<<<nbscat + cdiv(E1 + N0, BT), BT, 0, stream>>>(
        src0, dst0, src1, dst1, dsrc, ddst, rowptrAll,
        cursors, pairbuf, cnt2, cntD2, col1, colD, nbscat, nbins0);

    // ---- fused: graph0 colv fill + layer-0 dual GEMM (independent) ----
    binfill_dualmm_kernel<<<nbins0 + G0, BT, 0, stream>>>(
        pairbuf, rowptrAll, col0, N0, nbins0,
        X, WT(0), WT(1), b0, y0sb, y0nf8, N0, nt0);

    // x0 = y0s + mean_nbr(y0n)  (bf16 out)
    csr_agg_big<1><<<cdiv(N0, 8), BT, 0, stream>>>(y0nf8, rowptrAll, 0, col0,
        y0sb, nullptr, x0b, nullptr, nullptr, nullptr, nullptr, N0, 0);

    // ---- down pool: x1 = relu(mean_cluster(x0)) ----
    csr_agg_big<0><<<cdiv(N1, 8), BT, 0, stream>>>(x0b, rowptrAll + N0 + N1, E0 + E1,
        colD, nullptr, nullptr, x1bb, nullptr, nullptr, nullptr, nullptr, N1, 1);

    // ---- layer 1 SAGE (bf16 A, fp32 outs) ----
    dualmm_regb_kernel<<<nt1, BT, 0, stream>>>(x1bb, WT(2), WT(3), b1,
        nullptr, nullptr, nullptr, y1s, nullptr, y1n, nullptr, N1, nt1);
    csr_agg2_kernel<<<cdiv(N1, 4), BT, 0, stream>>>(y1n, rowptrAll + N0, E0, col1,
        y1s, y1s, N1, 1);

    // ---- layer 2: small dualmm (fp32 A -> C2/D2), big bf16-A w/ up-scatter ----
    dualmm_reg_kernel<<<nt1, BT, 0, stream>>>(y1s, WT(4), WT(6), nullptr,
        C2, D2, N1, nt1);
    dualmm_regb_kernel<<<G0, BT, 0, stream>>>(x0b, WT(5), WT(7), nullptr,
        ddst, C2, D2, nullptr, y2sb, nullptr, y2nf8, N0, nt0);

    // ---- layer 2 combine + fused readout + fused softmax partial ----
    csr_agg_big<1><<<cdiv(N0, 8), BT, 0, stream>>>(y2nf8, rowptrAll, 0, col0,
        y2sb, b2, nullptr, Wm, bm, zbuf, redpack, N0, 1);

    // ---- softmax normalize ----
    softmax_final_kernel<<<128, BT, 0, stream>>>(zbuf, redpack, out, N0);
}

// Round 12
// 319.290 us; speedup vs baseline: 136.6492x; 136.6492x over previous
//
#include <hip/hip_runtime.h>
#include <hip/hip_bf16.h>
#include <cstdint>

#define D_DIM 128
#define N0_C 50000
#define N1_C 5000
#define E0_C 800000
#define E1_C 80000
#define BIN_SHIFT 9          // 512 dst nodes per bin (graph0 fill)

typedef __attribute__((ext_vector_type(8))) short bf16x8;
typedef __attribute__((ext_vector_type(4))) float f32x4;
typedef __attribute__((ext_vector_type(2))) float f32x2;

__device__ __forceinline__ ushort f2bf_rne(float x) {
    unsigned int u = __float_as_uint(x);
    return (ushort)((u + 0x7FFFu + ((u >> 16) & 1u)) >> 16);
}
__device__ __forceinline__ float bf2f(ushort h) {
    return __uint_as_float(((unsigned int)h) << 16);
}
__device__ __forceinline__ int imin(int a, int b) { return a < b ? a : b; }
__device__ __forceinline__ void online2(float& m, float& s, float mo, float so) {
    if (mo > m) { s = s * __expf(m - mo) + so; m = mo; }
    else s += so * __expf(mo - m);
}

// ---------------------------------------------------------------------------
// prep: fused histogram over [dst0|dst1|ddst]  +  weight prep (independent)
// wt mats: 0:W0s 1:W0n 2:W1s 3:W1n 4:W2s_top 5:W2s_bot 6:W2n_top 7:W2n_bot
// ---------------------------------------------------------------------------
__global__ __launch_bounds__(256) void prep_kernel(
    const int* __restrict__ dst0, const int* __restrict__ dst1,
    const int* __restrict__ ddst, int* __restrict__ cnt,
    const float* __restrict__ W0s, const float* __restrict__ W0n,
    const float* __restrict__ W1s, const float* __restrict__ W1n,
    const float* __restrict__ W2s, const float* __restrict__ W2n,
    ushort* __restrict__ wt, int nbh) {
    int b = blockIdx.x, t = threadIdx.x;
    if (b < nbh) {
        int e = b * 256 + t;
        if (e < E0_C) atomicAdd(&cnt[dst0[e]], 1);
        else if (e < E0_C + E1_C) atomicAdd(&cnt[N0_C + dst1[e - E0_C]], 1);
        else if (e < E0_C + E1_C + N0_C) atomicAdd(&cnt[N0_C + N1_C + ddst[e - E0_C - E1_C]], 1);
    } else {
        int gi = (b - nbh) * 256 + t;
        int mi = gi >> 14, idx = gi & 16383;
        int k = idx >> 7, n = idx & 127;
        const float* src; int row = k;
        switch (mi) {
            case 0: src = W0s; break;
            case 1: src = W0n; break;
            case 2: src = W1s; break;
            case 3: src = W1n; break;
            case 4: src = W2s; break;
            case 5: src = W2s; row = k + 128; break;
            case 6: src = W2n; break;
            default: src = W2n; row = k + 128; break;
        }
        wt[(mi << 14) + n * 128 + k] = f2bf_rne(src[row * 128 + n]);
    }
}

// ---------------------------------------------------------------------------
// single-pass scan over cnt[n]: decoupled block-sum publication (all 59
// blocks co-resident); writes rowptr (inclusive at [i+1]) + graph0 cursors.
// ---------------------------------------------------------------------------
__global__ __launch_bounds__(256) void scan_onepass_kernel(
    const int* __restrict__ cnt, int* __restrict__ bflag,
    int* __restrict__ rowptr, int* __restrict__ cursors, int n) {
    __shared__ int wsum[4];
    __shared__ int boff_s;
    int b = blockIdx.x, t = threadIdx.x, lane = t & 63, w = t >> 6;
    int base = b * 1024 + t * 4;
    int v0 = 0, v1 = 0, v2 = 0, v3 = 0;
    if (base + 3 < n) { int4 q = *(const int4*)&cnt[base]; v0 = q.x; v1 = q.y; v2 = q.z; v3 = q.w; }
    else {
        if (base + 0 < n) v0 = cnt[base + 0];
        if (base + 1 < n) v1 = cnt[base + 1];
        if (base + 2 < n) v2 = cnt[base + 2];
        if (base + 3 < n) v3 = cnt[base + 3];
    }
    int s = v0 + v1 + v2 + v3;
    int x = s;
    #pragma unroll
    for (int off = 1; off < 64; off <<= 1) {
        int y = __shfl_up(x, off);
        if (lane >= off) x += y;
    }
    if (lane == 63) wsum[w] = x;
    __syncthreads();
    if (t == 0) {
        int run = 0;
        #pragma unroll
        for (int i = 0; i < 4; ++i) { int c = wsum[i]; wsum[i] = run; run += c; }
        atomicExch(&bflag[b], run + 1);          // publish local total (device scope)
    }
    if (w == 0) {
        int pv = 0;
        if (lane < b) {
            int v;
            while ((v = atomicAdd(&bflag[lane], 0)) == 0) {}
            pv = v - 1;
        }
        #pragma unroll
        for (int off = 32; off; off >>= 1) pv += __shfl_down(pv, off);
        if (lane == 0) boff_s = pv;
    }
    __syncthreads();
    int run = boff_s + wsum[w] + x - s;
    #pragma unroll
    for (int k = 0; k < 4; ++k) {
        int v = (k == 0) ? v0 : (k == 1) ? v1 : (k == 2) ? v2 : v3;
        int pos = base + k + 1;
        if (pos <= n) {
            run += v;
            rowptr[pos] = run;
            if ((pos & 511) == 0 && pos < N0_C) cursors[pos >> BIN_SHIFT] = run;
        }
    }
    if (b == 0 && t == 0) { rowptr[0] = 0; cursors[0] = 0; }
}

// ---------------------------------------------------------------------------
// scatfill: graph0 binned pair-scatter (blocks < nbscat) + small fills
// ---------------------------------------------------------------------------
__global__ __launch_bounds__(256) void scatfill_kernel(
    const int* __restrict__ src0, const int* __restrict__ dst0,
    const int* __restrict__ src1, const int* __restrict__ dst1,
    const int* __restrict__ dsrc, const int* __restrict__ ddst,
    const int* __restrict__ rowptrAll,
    int* __restrict__ cursors, int* __restrict__ pairs,
    int* __restrict__ cur1, int* __restrict__ curD,
    int* __restrict__ col1, int* __restrict__ colD,
    int nbscat, int nbins) {
    __shared__ int lcnt[128];
    __shared__ int sbase[128];
    int t = threadIdx.x;
    if (blockIdx.x < nbscat) {
        int e0 = blockIdx.x * 4096;
        if (t < 128) lcnt[t] = 0;
        __syncthreads();
        int lrank[16], dloc[16];
        #pragma unroll
        for (int i = 0; i < 16; ++i) {
            int e = e0 + t + i * 256;
            if (e < E0_C) {
                int d = dst0[e];
                dloc[i] = d;
                lrank[i] = atomicAdd(&lcnt[d >> BIN_SHIFT], 1);
            } else dloc[i] = -1;
        }
        __syncthreads();
        if (t < nbins && lcnt[t] > 0) sbase[t] = atomicAdd(&cursors[t], lcnt[t]);
        __syncthreads();
        #pragma unroll
        for (int i = 0; i < 16; ++i) {
            int e = e0 + t + i * 256;
            if (e < E0_C) {
                int d = dloc[i];
                int key = ((d & ((1 << BIN_SHIFT) - 1)) << 17) | src0[e];
                pairs[sbase[d >> BIN_SHIFT] + lrank[i]] = key;
            }
        }
    } else {
        int e = (blockIdx.x - nbscat) * 256 + t;
        if (e < E1_C) {
            int d = dst1[e];
            int p = atomicAdd(&cur1[d], 1);
            col1[rowptrAll[N0_C + d] - E0_C + p] = src1[e];
        } else if (e < E1_C + N0_C) {
            int i = e - E1_C;
            int d = ddst[i];
            int p = atomicAdd(&curD[d], 1);
            colD[rowptrAll[N0_C + N1_C + d] - E0_C - E1_C + p] = dsrc[i];
        }
    }
}

// ---------------------------------------------------------------------------
// fused: graph0 windowed colv fill (blocks < nbfill)  +  layer-0 dual GEMM
// dualmm: fp32 A hi/lo split, reg-resident B; O1 bf16 packed, O2 fp8 packed.
// ---------------------------------------------------------------------------
__global__ __launch_bounds__(256, 4) void binfill_dualmm_kernel(
    const int* __restrict__ pairs, const int* __restrict__ rowptr,
    int* __restrict__ colv, int Nfill, int nbfill,
    const float* __restrict__ A,
    const ushort* __restrict__ w1, const ushort* __restrict__ w2,
    const float* __restrict__ bias1,
    ushort* __restrict__ O1b, unsigned char* __restrict__ O2f8,
    int N, int ntiles) {
    __shared__ int rp[513];
    __shared__ int cur[512];
    const int tid = threadIdx.x;
    if (blockIdx.x < nbfill) {
        int b = blockIdx.x;
        int binbase = b << BIN_SHIFT;
        for (int i = tid; i < 513; i += 256) {
            int idx = binbase + i; if (idx > Nfill) idx = Nfill;
            rp[i] = rowptr[idx];
        }
        for (int i = tid; i < 512; i += 256) cur[i] = 0;
        __syncthreads();
        int beg = rp[0], end = rp[512];
        for (int i = beg + tid; i < end; i += 256) {
            int key = pairs[i];
            int local = key >> 17;
            int rank = atomicAdd(&cur[local], 1);
            colv[rp[local] + rank] = key & 0x1FFFF;
        }
        return;
    }
    // ---- dualmm part ----
    const int gstride = gridDim.x - nbfill;
    const int bid = blockIdx.x - nbfill;
    const int wave = tid >> 6, lane = tid & 63;
    const int m = lane & 15, quad = lane >> 4;
    const int colbase = wave * 32;
    bf16x8 bf[4][2][2];
    #pragma unroll
    for (int c = 0; c < 4; ++c)
        #pragma unroll
        for (int ct = 0; ct < 2; ++ct) {
            const size_t bo = (size_t)(colbase + ct * 16 + m) * 128 + c * 32 + quad * 8;
            bf[c][ct][0] = *(const bf16x8*)(w1 + bo);
            bf[c][ct][1] = *(const bf16x8*)(w2 + bo);
        }
    const f32x4 zero = {0.f, 0.f, 0.f, 0.f};
    for (int tile = bid; tile < ntiles; tile += gstride) {
        const int r0 = tile * 16;
        int ar = r0 + m; if (ar >= N) ar = N - 1;
        const float* arow = A + (size_t)ar * 128;
        f32x4 acc[2][2];
        acc[0][0] = zero; acc[0][1] = zero; acc[1][0] = zero; acc[1][1] = zero;
        #pragma unroll
        for (int c = 0; c < 4; ++c) {
            float4 a0 = *(const float4*)(arow + c * 32 + quad * 8);
            float4 a1 = *(const float4*)(arow + c * 32 + quad * 8 + 4);
            float av[8] = {a0.x, a0.y, a0.z, a0.w, a1.x, a1.y, a1.z, a1.w};
            bf16x8 afh, afl;
            #pragma unroll
            for (int i = 0; i < 8; ++i) {
                ushort h = f2bf_rne(av[i]);
                ushort l = f2bf_rne(av[i] - bf2f(h));
                afh[i] = (short)h; afl[i] = (short)l;
            }
            #pragma unroll
            for (int ct = 0; ct < 2; ++ct) {
                acc[ct][0] = __builtin_amdgcn_mfma_f32_16x16x32_bf16(afh, bf[c][ct][0], acc[ct][0], 0, 0, 0);
                acc[ct][0] = __builtin_amdgcn_mfma_f32_16x16x32_bf16(afl, bf[c][ct][0], acc[ct][0], 0, 0, 0);
                acc[ct][1] = __builtin_amdgcn_mfma_f32_16x16x32_bf16(afh, bf[c][ct][1], acc[ct][1], 0, 0, 0);
                acc[ct][1] = __builtin_amdgcn_mfma_f32_16x16x32_bf16(afl, bf[c][ct][1], acc[ct][1], 0, 0, 0);
            }
        }
        #pragma unroll
        for (int ct = 0; ct < 2; ++ct) {
            const int col = colbase + ct * 16 + m;
            float bv = bias1 ? bias1[col] : 0.f;
            #pragma unroll
            for (int reg = 0; reg < 4; ++reg) {
                int r = r0 + quad * 4 + reg;
                float o1 = acc[ct][0][reg] + bv;
                float o2 = acc[ct][1][reg];
                uint u1 = f2bf_rne(o1);
                uint p1 = (uint)__shfl_xor((int)u1, 1);
                float o2n = __shfl_xor(o2, 1);
                int pk = __builtin_amdgcn_cvt_pk_fp8_f32(o2, o2n, 0, false);
                int pk2 = __shfl_xor(pk, 2);
                if (r < N) {
                    if (!(m & 1)) *(uint*)&O1b[(size_t)r * D_DIM + col] = u1 | (p1 << 16);
                    if (!(m & 3)) *(uint*)&O2f8[(size_t)r * D_DIM + col] =
                        ((uint)pk & 0xFFFFu) | ((uint)pk2 << 16);
                }
            }
        }
    }
}

// ---------------------------------------------------------------------------
// standalone dual GEMM, fp32 A (hi/lo split), fp32 outs (layer-2 small C2/D2)
// ---------------------------------------------------------------------------
__global__ __launch_bounds__(256, 4) void dualmm_reg_kernel(
    const float* __restrict__ A,
    const ushort* __restrict__ w1, const ushort* __restrict__ w2,
    const float* __restrict__ bias1,
    float* __restrict__ O1f, float* __restrict__ O2f, int N, int ntiles) {
    const int tid = threadIdx.x;
    const int wave = tid >> 6, lane = tid & 63;
    const int m = lane & 15, quad = lane >> 4;
    const int colbase = wave * 32;
    bf16x8 bf[4][2][2];
    #pragma unroll
    for (int c = 0; c < 4; ++c)
        #pragma unroll
        for (int ct = 0; ct < 2; ++ct) {
            const size_t bo = (size_t)(colbase + ct * 16 + m) * 128 + c * 32 + quad * 8;
            bf[c][ct][0] = *(const bf16x8*)(w1 + bo);
            bf[c][ct][1] = *(const bf16x8*)(w2 + bo);
        }
    const f32x4 zero = {0.f, 0.f, 0.f, 0.f};
    for (int tile = blockIdx.x; tile < ntiles; tile += gridDim.x) {
        const int r0 = tile * 16;
        int ar = r0 + m; if (ar >= N) ar = N - 1;
        const float* arow = A + (size_t)ar * 128;
        f32x4 acc[2][2];
        acc[0][0] = zero; acc[0][1] = zero; acc[1][0] = zero; acc[1][1] = zero;
        #pragma unroll
        for (int c = 0; c < 4; ++c) {
            float4 a0 = *(const float4*)(arow + c * 32 + quad * 8);
            float4 a1 = *(const float4*)(arow + c * 32 + quad * 8 + 4);
            float av[8] = {a0.x, a0.y, a0.z, a0.w, a1.x, a1.y, a1.z, a1.w};
            bf16x8 afh, afl;
            #pragma unroll
            for (int i = 0; i < 8; ++i) {
                ushort h = f2bf_rne(av[i]);
                ushort l = f2bf_rne(av[i] - bf2f(h));
                afh[i] = (short)h; afl[i] = (short)l;
            }
            #pragma unroll
            for (int ct = 0; ct < 2; ++ct) {
                acc[ct][0] = __builtin_amdgcn_mfma_f32_16x16x32_bf16(afh, bf[c][ct][0], acc[ct][0], 0, 0, 0);
                acc[ct][0] = __builtin_amdgcn_mfma_f32_16x16x32_bf16(afl, bf[c][ct][0], acc[ct][0], 0, 0, 0);
                acc[ct][1] = __builtin_amdgcn_mfma_f32_16x16x32_bf16(afh, bf[c][ct][1], acc[ct][1], 0, 0, 0);
                acc[ct][1] = __builtin_amdgcn_mfma_f32_16x16x32_bf16(afl, bf[c][ct][1], acc[ct][1], 0, 0, 0);
            }
        }
        #pragma unroll
        for (int ct = 0; ct < 2; ++ct) {
            const int col = colbase + ct * 16 + m;
            float bv = bias1 ? bias1[col] : 0.f;
            #pragma unroll
            for (int reg = 0; reg < 4; ++reg) {
                int r = r0 + quad * 4 + reg;
                if (r < N) {
                    size_t o = (size_t)r * D_DIM + col;
                    O1f[o] = acc[ct][0][reg] + bv;
                    O2f[o] = acc[ct][1][reg];
                }
            }
        }
    }
}

// bf16-A variant: optional bias, optional C2/D2 gather-add, fp32 or bf16+fp8 outs
__global__ __launch_bounds__(256, 4) void dualmm_regb_kernel(
    const ushort* __restrict__ Ab,
    const ushort* __restrict__ w1, const ushort* __restrict__ w2,
    const float* __restrict__ bias1,
    const int* __restrict__ ddst,
    const float* __restrict__ C2g, const float* __restrict__ D2g,
    float* __restrict__ O1f, ushort* __restrict__ O1b,
    float* __restrict__ O2f, unsigned char* __restrict__ O2f8,
    int N, int ntiles) {
    const int tid = threadIdx.x;
    const int wave = tid >> 6, lane = tid & 63;
    const int m = lane & 15, quad = lane >> 4;
    const int colbase = wave * 32;
    bf16x8 bf[4][2][2];
    #pragma unroll
    for (int c = 0; c < 4; ++c)
        #pragma unroll
        for (int ct = 0; ct < 2; ++ct) {
            const size_t bo = (size_t)(colbase + ct * 16 + m) * 128 + c * 32 + quad * 8;
            bf[c][ct][0] = *(const bf16x8*)(w1 + bo);
            bf[c][ct][1] = *(const bf16x8*)(w2 + bo);
        }
    const f32x4 zero = {0.f, 0.f, 0.f, 0.f};
    for (int tile = blockIdx.x; tile < ntiles; tile += gridDim.x) {
        const int r0 = tile * 16;
        int ar = r0 + m; if (ar >= N) ar = N - 1;
        const ushort* arow = Ab + (size_t)ar * 128;
        f32x4 acc[2][2];
        acc[0][0] = zero; acc[0][1] = zero; acc[1][0] = zero; acc[1][1] = zero;
        #pragma unroll
        for (int c = 0; c < 4; ++c) {
            bf16x8 af = *(const bf16x8*)(arow + c * 32 + quad * 8);
            #pragma unroll
            for (int ct = 0; ct < 2; ++ct) {
                acc[ct][0] = __builtin_amdgcn_mfma_f32_16x16x32_bf16(af, bf[c][ct][0], acc[ct][0], 0, 0, 0);
                acc[ct][1] = __builtin_amdgcn_mfma_f32_16x16x32_bf16(af, bf[c][ct][1], acc[ct][1], 0, 0, 0);
            }
        }
        int rr[4], cc[4];
        #pragma unroll
        for (int reg = 0; reg < 4; ++reg) {
            rr[reg] = r0 + quad * 4 + reg;
            cc[reg] = (ddst && rr[reg] < N) ? ddst[rr[reg]] : 0;
        }
        #pragma unroll
        for (int ct = 0; ct < 2; ++ct) {
            const int col = colbase + ct * 16 + m;
            float bv = bias1 ? bias1[col] : 0.f;
            #pragma unroll
            for (int reg = 0; reg < 4; ++reg) {
                int r = rr[reg];
                float g1 = (ddst && r < N) ? C2g[(size_t)cc[reg] * D_DIM + col] : 0.f;
                float g2 = (ddst && r < N) ? D2g[(size_t)cc[reg] * D_DIM + col] : 0.f;
                float o1 = acc[ct][0][reg] + bv + g1;
                float o2 = acc[ct][1][reg] + g2;
                if (O1b) {
                    uint u1 = f2bf_rne(o1);
                    uint p1 = (uint)__shfl_xor((int)u1, 1);
                    float o2n = __shfl_xor(o2, 1);
                    int pk = __builtin_amdgcn_cvt_pk_fp8_f32(o2, o2n, 0, false);
                    int pk2 = __shfl_xor(pk, 2);
                    if (r < N) {
                        if (!(m & 1)) *(uint*)&O1b[(size_t)r * D_DIM + col] = u1 | (p1 << 16);
                        if (!(m & 3)) *(uint*)&O2f8[(size_t)r * D_DIM + col] =
                            ((uint)pk & 0xFFFFu) | ((uint)pk2 << 16);
                    }
                } else if (r < N) {
                    size_t o = (size_t)r * D_DIM + col;
                    O1f[o] = o1; O2f[o] = o2;
                }
            }
        }
    }
}

// ---------------------------------------------------------------------------
// fp32 CSR gather-aggregate (small graph1): wave/node, float4/lane
// ---------------------------------------------------------------------------
__global__ __launch_bounds__(256) void csr_agg2_kernel(
    const float* __restrict__ feat, const int* __restrict__ rowptr, int rbase,
    const int* __restrict__ colv, const float* __restrict__ addv,
    float* __restrict__ out, int Ndst, int do_relu) {
    int gt = blockIdx.x * blockDim.x + threadIdx.x;
    int wid = gt >> 6;
    if (wid >= Ndst) return;
    int lane = threadIdx.x & 63;
    int half = lane >> 5, li = lane & 31;
    const int f4 = li * 4;
    float4 acc = make_float4(0.f, 0.f, 0.f, 0.f);
    int beg = rowptr[wid] - rbase, end = rowptr[wid + 1] - rbase;
    int deg = end - beg;
    for (int j = beg + half; j < end; j += 8) {
        int i1 = imin(j + 2, end - 1), i2 = imin(j + 4, end - 1), i3 = imin(j + 6, end - 1);
        int r0 = colv[j], r1 = colv[i1], r2 = colv[i2], r3 = colv[i3];
        float4 v0 = *(const float4*)&feat[(size_t)r0 * D_DIM + f4];
        float4 v1 = *(const float4*)&feat[(size_t)r1 * D_DIM + f4];
        float4 v2 = *(const float4*)&feat[(size_t)r2 * D_DIM + f4];
        float4 v3 = *(const float4*)&feat[(size_t)r3 * D_DIM + f4];
        acc.x += v0.x; acc.y += v0.y; acc.z += v0.z; acc.w += v0.w;
        if (j + 2 < end) { acc.x += v1.x; acc.y += v1.y; acc.z += v1.z; acc.w += v1.w; }
        if (j + 4 < end) { acc.x += v2.x; acc.y += v2.y; acc.z += v2.z; acc.w += v2.w; }
        if (j + 6 < end) { acc.x += v3.x; acc.y += v3.y; acc.z += v3.z; acc.w += v3.w; }
    }
    acc.x += __shfl_xor(acc.x, 32);
    acc.y += __shfl_xor(acc.y, 32);
    acc.z += __shfl_xor(acc.z, 32);
    acc.w += __shfl_xor(acc.w, 32);
    float invd = 1.f / fmaxf((float)deg, 1.f);
    acc.x *= invd; acc.y *= invd; acc.z *= invd; acc.w *= invd;
    if (addv) {
        float4 v = *(const float4*)&addv[(size_t)wid * D_DIM + f4];
        acc.x += v.x; acc.y += v.y; acc.z += v.z; acc.w += v.w;
    }
    if (do_relu) {
        acc.x = fmaxf(acc.x, 0.f); acc.y = fmaxf(acc.y, 0.f);
        acc.z = fmaxf(acc.z, 0.f); acc.w = fmaxf(acc.w, 0.f);
    }
    if (half == 0)
        *(float4*)&out[(size_t)wid * D_DIM + f4] = acc;
}

// ---------------------------------------------------------------------------
// big CSR gather-aggregate, 2 nodes/wave; FP8 plane or bf16 plane.
// Optional fused readout z = relu(...)@Wm + bm (z write only — softmax
// reduction is a separate 64-block kernel; single-location CAS merge was a
// 100x regression in r11: 6250 contenders on one line).
// ---------------------------------------------------------------------------
__device__ __forceinline__ void acc8_add_bf(float* acc, uint4 r) {
    acc[0] += __uint_as_float(r.x << 16);
    acc[1] += __uint_as_float(r.x & 0xFFFF0000u);
    acc[2] += __uint_as_float(r.y << 16);
    acc[3] += __uint_as_float(r.y & 0xFFFF0000u);
    acc[4] += __uint_as_float(r.z << 16);
    acc[5] += __uint_as_float(r.z & 0xFFFF0000u);
    acc[6] += __uint_as_float(r.w << 16);
    acc[7] += __uint_as_float(r.w & 0xFFFF0000u);
}
__device__ __forceinline__ void acc8_add_f8(float* acc, uint2 r) {
    f32x2 a = __builtin_amdgcn_cvt_pk_f32_fp8((int)r.x, false);
    f32x2 b = __builtin_amdgcn_cvt_pk_f32_fp8((int)r.x, true);
    f32x2 c = __builtin_amdgcn_cvt_pk_f32_fp8((int)r.y, false);
    f32x2 d = __builtin_amdgcn_cvt_pk_f32_fp8((int)r.y, true);
    acc[0] += a[0]; acc[1] += a[1]; acc[2] += b[0]; acc[3] += b[1];
    acc[4] += c[0]; acc[5] += c[1]; acc[6] += d[0]; acc[7] += d[1];
}

template <int FP8>
__global__ __launch_bounds__(256) void csr_agg_big(
    const void* __restrict__ featv, const int* __restrict__ rowptr, int rbase,
    const int* __restrict__ colv,
    const ushort* __restrict__ addvb, const float* __restrict__ bias,
    ushort* __restrict__ outb,
    const float* __restrict__ Wm, const float* __restrict__ bm,
    float* __restrict__ z, int Ndst, int do_relu) {
    const char* feat = (const char*)featv;
    int gt = blockIdx.x * blockDim.x + threadIdx.x;
    int wp = gt >> 6;
    int nA = wp * 2;
    if (nA >= Ndst) return;
    int nB = nA + 1;
    bool hasB = (nB < Ndst);
    int lane = threadIdx.x & 63;
    int q = lane >> 4, li = lane & 15;
    float accA[8], accB[8];
    #pragma unroll
    for (int i = 0; i < 8; ++i) { accA[i] = 0.f; accB[i] = 0.f; }
    int begA = rowptr[nA] - rbase, endA = rowptr[nA + 1] - rbase;
    int begB = 0, endB = 0;
    if (hasB) { begB = endA; endB = rowptr[nB + 1] - rbase; }
    int degA = endA - begA, degB = endB - begB;
    int lastA = (degA > 0) ? endA - 1 : 0;
    int lastB = (degB > 0) ? endB - 1 : 0;
    int jA = begA + q, jB = begB + q;
    while (jA < endA || jB < endB) {
        int ia[4], ib[4];
        #pragma unroll
        for (int k = 0; k < 4; ++k) {
            ia[k] = imin(jA + 4 * k, lastA);
            ib[k] = imin(jB + 4 * k, lastB);
        }
        if (FP8) {
            uint2 va[4], vb[4];
            #pragma unroll
            for (int k = 0; k < 4; ++k) {
                int ra = colv[ia[k]];
                va[k] = *(const uint2*)(feat + (size_t)ra * 128 + li * 8);
            }
            #pragma unroll
            for (int k = 0; k < 4; ++k) {
                int rb = colv[ib[k]];
                vb[k] = *(const uint2*)(feat + (size_t)rb * 128 + li * 8);
            }
            #pragma unroll
            for (int k = 0; k < 4; ++k) {
                if (jA + 4 * k < endA) acc8_add_f8(accA, va[k]);
                if (jB + 4 * k < endB) acc8_add_f8(accB, vb[k]);
            }
        } else {
            uint4 va[4], vb[4];
            #pragma unroll
            for (int k = 0; k < 4; ++k) {
                int ra = colv[ia[k]];
                va[k] = *(const uint4*)(feat + (size_t)ra * 256 + li * 16);
            }
            #pragma unroll
            for (int k = 0; k < 4; ++k) {
                int rb = colv[ib[k]];
                vb[k] = *(const uint4*)(feat + (size_t)rb * 256 + li * 16);
            }
            #pragma unroll
            for (int k = 0; k < 4; ++k) {
                if (jA + 4 * k < endA) acc8_add_bf(accA, va[k]);
                if (jB + 4 * k < endB) acc8_add_bf(accB, vb[k]);
            }
        }
        jA += 16; jB += 16;
    }
    const int f8 = li * 8;
    #pragma unroll
    for (int i = 0; i < 8; ++i) {
        accA[i] += __shfl_xor(accA[i], 16);
        accA[i] += __shfl_xor(accA[i], 32);
        accB[i] += __shfl_xor(accB[i], 16);
        accB[i] += __shfl_xor(accB[i], 32);
    }
    float invA = 1.f / fmaxf((float)degA, 1.f);
    float invB = 1.f / fmaxf((float)degB, 1.f);
    #pragma unroll
    for (int i = 0; i < 8; ++i) { accA[i] *= invA; accB[i] *= invB; }
    if (addvb) {
        uint4 a = *(const uint4*)&addvb[(size_t)nA * D_DIM + f8];
        acc8_add_bf(accA, a);
        if (hasB) {
            uint4 b = *(const uint4*)&addvb[(size_t)nB * D_DIM + f8];
            acc8_add_bf(accB, b);
        }
    }
    if (bias) {
        float4 b0 = *(const float4*)&bias[f8];
        float4 b1 = *(const float4*)&bias[f8 + 4];
        accA[0] += b0.x; accA[1] += b0.y; accA[2] += b0.z; accA[3] += b0.w;
        accA[4] += b1.x; accA[5] += b1.y; accA[6] += b1.z; accA[7] += b1.w;
        accB[0] += b0.x; accB[1] += b0.y; accB[2] += b0.z; accB[3] += b0.w;
        accB[4] += b1.x; accB[5] += b1.y; accB[6] += b1.z; accB[7] += b1.w;
    }
    if (do_relu) {
        #pragma unroll
        for (int i = 0; i < 8; ++i) {
            accA[i] = fmaxf(accA[i], 0.f);
            accB[i] = fmaxf(accB[i], 0.f);
        }
    }
    if (outb) {
        if (q == 0) {
            uint4 o;
            o.x = (uint)f2bf_rne(accA[0]) | ((uint)f2bf_rne(accA[1]) << 16);
            o.y = (uint)f2bf_rne(accA[2]) | ((uint)f2bf_rne(accA[3]) << 16);
            o.z = (uint)f2bf_rne(accA[4]) | ((uint)f2bf_rne(accA[5]) << 16);
            o.w = (uint)f2bf_rne(accA[6]) | ((uint)f2bf_rne(accA[7]) << 16);
            *(uint4*)&outb[(size_t)nA * D_DIM + f8] = o;
        } else if (q == 1 && hasB) {
            uint4 o;
            o.x = (uint)f2bf_rne(accB[0]) | ((uint)f2bf_rne(accB[1]) << 16);
            o.y = (uint)f2bf_rne(accB[2]) | ((uint)f2bf_rne(accB[3]) << 16);
            o.z = (uint)f2bf_rne(accB[4]) | ((uint)f2bf_rne(accB[5]) << 16);
            o.w = (uint)f2bf_rne(accB[6]) | ((uint)f2bf_rne(accB[7]) << 16);
            *(uint4*)&outb[(size_t)nB * D_DIM + f8] = o;
        }
    }
    if (z) {
        float4 w0 = *(const float4*)&Wm[f8];
        float4 w1 = *(const float4*)&Wm[f8 + 4];
        float p = 0.f;
        if (q == 0)
            p = accA[0] * w0.x + accA[1] * w0.y + accA[2] * w0.z + accA[3] * w0.w
              + accA[4] * w1.x + accA[5] * w1.y + accA[6] * w1.z + accA[7] * w1.w;
        else if (q == 1)
            p = accB[0] * w0.x + accB[1] * w0.y + accB[2] * w0.z + accB[3] * w0.w
              + accB[4] * w1.x + accB[5] * w1.y + accB[6] * w1.z + accB[7] * w1.w;
        #pragma unroll
        for (int off = 8; off > 0; off >>= 1) p += __shfl_down(p, off);
        if (lane == 0) z[nA] = p + bm[0];
        if (lane == 16 && hasB) z[nB] = p + bm[0];
    }
}

// ---------------------------------------------------------------------------
// softmax: 64-block online partial, then final (re-merges 64 partials/block)
// ---------------------------------------------------------------------------
__global__ __launch_bounds__(256) void softmax_partial_kernel(
    const float* __restrict__ z, float* __restrict__ red, int N, int nblk) {
    __shared__ float sm[4], ss[4];
    int t = threadIdx.x, b = blockIdx.x;
    int lane = t & 63, w = t >> 6;
    float m = -1e30f, s = 0.f;
    for (int i = b * 256 + t; i < N; i += nblk * 256) {
        float v = z[i];
        if (v > m) { s = s * __expf(m - v) + 1.f; m = v; }
        else s += __expf(v - m);
    }
    #pragma unroll
    for (int off = 32; off > 0; off >>= 1) {
        float mo = __shfl_down(m, off), so = __shfl_down(s, off);
        online2(m, s, mo, so);
    }
    if (lane == 0) { sm[w] = m; ss[w] = s; }
    __syncthreads();
    if (t == 0) {
        for (int i = 1; i < 4; ++i) online2(m, s, sm[i], ss[i]);
        red[2 + 2 * b] = m; red[3 + 2 * b] = s;
    }
}

__global__ __launch_bounds__(256) void softmax_final_kernel(
    const float* __restrict__ z, const float* __restrict__ red,
    float* __restrict__ out, int N, int B) {
    __shared__ float sm_s, ss_s;
    int t = threadIdx.x;
    if (t < 64) {
        float m = -1e30f, s = 0.f;
        if (t < B) { m = red[2 + 2 * t]; s = red[3 + 2 * t]; }
        #pragma unroll
        for (int off = 32; off > 0; off >>= 1) {
            float mo = __shfl_down(m, off), so = __shfl_down(s, off);
            online2(m, s, mo, so);
        }
        if (t == 0) { sm_s = m; ss_s = s; }
    }
    __syncthreads();
    float mx = sm_s, sum = ss_s;
    for (int i = blockIdx.x * 256 + t; i < N; i += gridDim.x * 256)
        out[i] = expf(z[i] - mx) / sum;
}

// ---------------------------------------------------------------------------
// Host launcher
// ---------------------------------------------------------------------------
static inline char* align_up(char* p, size_t a) {
    return (char*)(((uintptr_t)p + a - 1) & ~(uintptr_t)(a - 1));
}

extern "C" void kernel_launch(void* const* d_in, const int* in_sizes, int n_in,
                              void* d_out, int out_size, void* d_ws, size_t ws_size,
                              hipStream_t stream) {
    const int N0 = N0_C, N1 = N1_C, E0 = E0_C, E1 = E1_C;
    const float* X   = (const float*)d_in[0];
    const float* W0s = (const float*)d_in[1];
    const float* W0n = (const float*)d_in[2];
    const float* b0  = (const float*)d_in[3];
    const float* W1s = (const float*)d_in[4];
    const float* W1n = (const float*)d_in[5];
    const float* b1  = (const float*)d_in[6];
    const float* W2s = (const float*)d_in[7];
    const float* W2n = (const float*)d_in[8];
    const float* b2  = (const float*)d_in[9];
    const float* Wm  = (const float*)d_in[10];
    const float* bm  = (const float*)d_in[11];
    const int* src0  = (const int*)d_in[12];
    const int* dst0  = (const int*)d_in[13];
    const int* src1  = (const int*)d_in[14];
    const int* dst1  = (const int*)d_in[15];
    const int* dsrc  = (const int*)d_in[16];
    const int* ddst  = (const int*)d_in[17];
    float* out = (float*)d_out;

    char* p = (char*)d_ws;
    const size_t FB = (size_t)N0 * D_DIM;
    const size_t SB = (size_t)N1 * D_DIM;
    auto grab_f = [&](size_t nf) { p = align_up(p, 256); float* r = (float*)p; p += nf * 4; return r; };
    auto grab_i = [&](size_t ni) { p = align_up(p, 256); int* r = (int*)p; p += ni * 4; return r; };
    auto grab_u = [&](size_t nu) { p = align_up(p, 256); ushort* r = (ushort*)p; p += nu * 2; return r; };
    auto grab_b = [&](size_t nb) { p = align_up(p, 256); unsigned char* r = (unsigned char*)p; p += nb; return r; };

    const int NC = N0 + 2 * N1;
    // zero-init region: [cntAll NC | cnt2 N1 | cntD2 N1 | bflag 64]
    int* zeroRegion = grab_i((size_t)NC + 2 * N1 + 64);
    int* cntAll = zeroRegion;
    int* cnt2 = zeroRegion + NC;
    int* cntD2 = zeroRegion + NC + N1;
    int* bflag = zeroRegion + NC + 2 * N1;

    float* y1s  = grab_f(SB);   // -> x1f
    float* y1n  = grab_f(SB);
    float* C2   = grab_f(SB);
    float* D2   = grab_f(SB);
    float* zbuf = grab_f(N0);
    float* red  = grab_f(256);
    ushort* y0sb = grab_u(FB);
    ushort* x0b  = grab_u(FB);
    ushort* y2sb = grab_u(FB);
    ushort* x1bb = grab_u(SB);
    unsigned char* y0nf8 = grab_b(FB);
    unsigned char* y2nf8 = grab_b(FB);
    ushort* wt   = grab_u(8 * 16384);
    int* rowptrAll = grab_i(NC + 1);
    int* cursors = grab_i(128);
    int* col0 = grab_i(E0);
    int* col1 = grab_i(E1);
    int* colD = grab_i(N0);
    int* pairbuf = grab_i((size_t)E0);
    (void)ws_size; (void)n_in; (void)in_sizes; (void)out_size;

    const int BT = 256;
    auto cdiv = [](int a, int b) { return (a + b - 1) / b; };
    auto WT = [&](int mi) { return wt + ((size_t)mi << 14); };
    const int nbins0 = (N0 + (1 << BIN_SHIFT) - 1) >> BIN_SHIFT;   // 98
    const int nt0 = cdiv(N0, 16);
    const int nt1 = cdiv(N1, 16);
    const int G0 = 1024;

    // ---- one memset for all counters/flags ----
    hipMemsetAsync(zeroRegion, 0, ((size_t)NC + 2 * N1 + 64) * 4, stream);

    // ---- CSR build + weight prep ----
    const int nbh = cdiv(E0 + E1 + N0, BT);
    prep_kernel<<<nbh + 512, BT, 0, stream>>>(dst0, dst1, ddst, cntAll,
        W0s, W0n, W1s, W1n, W2s, W2n, wt, nbh);
    const int NB = cdiv(NC, 1024);                     // 59 blocks, co-resident
    scan_onepass_kernel<<<NB, BT, 0, stream>>>(cntAll, bflag, rowptrAll, cursors, NC);
    const int nbscat = cdiv(E0, 4096);
    scatfill_kernel<<<nbscat + cdiv(E1 + N0, BT), BT, 0, stream>>>(
        src0, dst0, src1, dst1, dsrc, ddst, rowptrAll,
        cursors, pairbuf, cnt2, cntD2, col1, colD, nbscat, nbins0);

    // ---- fused: graph0 colv fill + layer-0 dual GEMM (independent) ----
    binfill_dualmm_kernel<<<nbins0 + G0, BT, 0, stream>>>(
        pairbuf, rowptrAll, col0, N0, nbins0,
        X, WT(0), WT(1), b0, y0sb, y0nf8, N0, nt0);

    // x0 = y0s + mean_nbr(y0n)  (bf16 out)
    csr_agg_big<1><<<cdiv(N0, 8), BT, 0, stream>>>(y0nf8, rowptrAll, 0, col0,
        y0sb, nullptr, x0b, nullptr, nullptr, nullptr, N0, 0);

    // ---- down pool: x1 = relu(mean_cluster(x0)) ----
    csr_agg_big<0><<<cdiv(N1, 8), BT, 0, stream>>>(x0b, rowptrAll + N0 + N1, E0 + E1,
        colD, nullptr, nullptr, x1bb, nullptr, nullptr, nullptr, N1, 1);

    // ---- layer 1 SAGE (bf16 A, fp32 outs) ----
    dualmm_regb_kernel<<<nt1, BT, 0, stream>>>(x1bb, WT(2), WT(3), b1,
        nullptr, nullptr, nullptr, y1s, nullptr, y1n, nullptr, N1, nt1);
    csr_agg2_kernel<<<cdiv(N1, 4), BT, 0, stream>>>(y1n, rowptrAll + N0, E0, col1,
        y1s, y1s, N1, 1);

    // ---- layer 2: small dualmm (fp32 A -> C2/D2), big bf16-A w/ up-scatter ----
    dualmm_reg_kernel<<<nt1, BT, 0, stream>>>(y1s, WT(4), WT(6), nullptr,
        C2, D2, N1, nt1);
    dualmm_regb_kernel<<<G0, BT, 0, stream>>>(x0b, WT(5), WT(7), nullptr,
        ddst, C2, D2, nullptr, y2sb, nullptr, y2nf8, N0, nt0);

    // ---- layer 2 combine + fused readout ----
    csr_agg_big<1><<<cdiv(N0, 8), BT, 0, stream>>>(y2nf8, rowptrAll, 0, col0,
        y2sb, b2, nullptr, Wm, bm, zbuf, N0, 1);

    // ---- softmax over nodes ----
    softmax_partial_kernel<<<64, BT, 0, stream>>>(zbuf, red, N0, 64);
    softmax_final_kernel<<<128, BT, 0, stream>>>(zbuf, red, out, N0, 64);
}